// Round 1
// baseline (1359.221 us; speedup 1.0000x reference)
//
#include <hip/hip_runtime.h>
#include <math.h>

#define N0   17186
#define FIN  6
#define H1C  64
#define H2C  32
#define KSEL 12031
#define BATCH 64
#define NE   500000
#define NT   (BATCH * N0)

typedef unsigned int uint;
typedef unsigned char uchar;

__device__ __forceinline__ uint keyOf(float f) {
    uint u = __float_as_uint(f);
    return (u & 0x80000000u) ? ~u : (u | 0x80000000u);
}

// ---------- edge dtype detection / normalization ----------
__global__ void k_detect(const uint* ei, int* flag64) {
    __shared__ int any;
    if (threadIdx.x == 0) any = 0;
    __syncthreads();
    for (int i = threadIdx.x; i < 1024; i += blockDim.x)
        if (ei[2 * i + 1] != 0u) any = 1;
    __syncthreads();
    if (threadIdx.x == 0) *flag64 = any ? 0 : 1;
}

__global__ void k_convert(const void* ei, const int* flag64, int* src, int* dst) {
    int f = *flag64;
    int stride = gridDim.x * blockDim.x;
    for (int i = blockIdx.x * blockDim.x + threadIdx.x; i < 2 * NE; i += stride) {
        int v = f ? (int)((const long long*)ei)[i] : ((const int*)ei)[i];
        if (i < NE) src[i] = v; else dst[i - NE] = v;
    }
}

// ---------- conv1 (graph 0 only has edges) ----------
__global__ void k_deg(const int* dst, uint* deg) {
    int e = blockIdx.x * blockDim.x + threadIdx.x;
    if (e < NE) atomicAdd(&deg[dst[e]], 1u);
}

__global__ void k_xw1(const float* x, const float* W1, float* xw1) {
    int t = blockIdx.x * blockDim.x + threadIdx.x;
    if (t >= N0 * H1C) return;
    int i = t >> 6, h = t & 63;
    float acc = 0.f;
#pragma unroll
    for (int f = 0; f < FIN; f++) acc += x[i * FIN + f] * W1[f * H1C + h];
    xw1[t] = acc;
}

__global__ void k_dinv(const uint* deg, float* dinv) {
    int i = blockIdx.x * blockDim.x + threadIdx.x;
    if (i < N0) dinv[i] = rsqrtf(1.0f + (float)deg[i]);
}

__global__ void k_msg1(const int* src, const int* dst, const float* dinv,
                       const float* xw1, float* acc1) {
    int gt = blockIdx.x * blockDim.x + threadIdx.x;
    int e = gt >> 6, lane = gt & 63;
    if (e >= NE) return;
    int s = src[e], d = dst[e];
    float norm = dinv[s] * dinv[d];
    atomicAdd(&acc1[d * H1C + lane], xw1[s * H1C + lane] * norm);
}

__global__ void k_fin1(const float* xw1, const float* dinv, const float* b1,
                       float* acc1 /* in: msg sum, out: h1 */) {
    int t = blockIdx.x * blockDim.x + threadIdx.x;
    if (t >= N0 * H1C) return;
    int i = t >> 6, h = t & 63;
    float di = dinv[i];
    float v = acc1[t] + xw1[t] * di * di + b1[h];
    acc1[t] = fmaxf(v, 0.f);
}

// ---------- pooling score ----------
__global__ void k_h1w(const float* h1, const float* Wp, float* h1w) {
    int gt = blockIdx.x * blockDim.x + threadIdx.x;
    int i = gt >> 6, lane = gt & 63;
    if (i >= N0) return;
    float v = h1[i * H1C + lane] * Wp[lane];
#pragma unroll
    for (int o = 32; o > 0; o >>= 1) v += __shfl_xor(v, o, 64);
    if (lane == 0) h1w[i] = v;
}

__global__ void k_smsg(const int* src, const int* dst, const float* dinv,
                       const float* h1w, float* sacc) {
    int e = blockIdx.x * blockDim.x + threadIdx.x;
    if (e < NE) {
        int s = src[e], d = dst[e];
        atomicAdd(&sacc[d], h1w[s] * dinv[s] * dinv[d]);
    }
}

__global__ void k_score0(const float* sacc, const float* h1w, const float* dinv,
                         const float* bp, float* score) {
    int i = blockIdx.x * blockDim.x + threadIdx.x;
    if (i < N0) {
        float di = dinv[i];
        score[i] = sacc[i] + h1w[i] * di * di + bp[0];
    }
}

// graphs 1..63: score = relu(x@W1+b1) . Wp + bp   (no edges)
__global__ void k_score_rest(const float* x, const float* W1, const float* b1,
                             const float* Wp, const float* bp, float* score) {
    int gt = blockIdx.x * blockDim.x + threadIdx.x;
    int w = gt >> 6, lane = gt & 63;
    int n = N0 + w;
    if (n >= NT) return;
    float acc = b1[lane];
#pragma unroll
    for (int f = 0; f < FIN; f++) acc += x[(size_t)n * FIN + f] * W1[f * H1C + lane];
    float v = fmaxf(acc, 0.f) * Wp[lane];
#pragma unroll
    for (int o = 32; o > 0; o >>= 1) v += __shfl_xor(v, o, 64);
    if (lane == 0) score[n] = v + bp[0];
}

// ---------- per-graph top-K selection (radix select on float keys) ----------
__global__ void k_topk(const float* score, uchar* sel) {
    int g = blockIdx.x;
    const float* sc = score + (size_t)g * N0;
    uchar* sl = sel + (size_t)g * N0;
    __shared__ uint hist[256];
    __shared__ uint shPrefix, shWant;
    __shared__ uint scanbuf[256];
    int tid = threadIdx.x;
    uint prefix = 0, want = KSEL;
    for (int pass = 0; pass < 4; pass++) {
        int shift = 24 - 8 * pass;
        hist[tid] = 0;
        __syncthreads();
        for (int i = tid; i < N0; i += 256) {
            uint k = keyOf(sc[i]);
            bool active = (pass == 0) || ((k >> (shift + 8)) == prefix);
            if (active) atomicAdd(&hist[(k >> shift) & 255], 1u);
        }
        __syncthreads();
        if (tid == 0) {
            uint cum = 0; int d = 255;
            for (; d > 0; d--) { cum += hist[d]; if (cum >= want) break; }
            if (cum < want) cum += hist[0];           // d==0 fallthrough
            shWant = want - (cum - hist[d]);
            shPrefix = (prefix << 8) | (uint)d;
        }
        __syncthreads();
        prefix = shPrefix; want = shWant;
        __syncthreads();
    }
    uint T = prefix, needEq = want;
    uint runningEq = 0;
    for (int base = 0; base < N0; base += 256) {
        int i = base + tid;
        uint k = (i < N0) ? keyOf(sc[i]) : 0u;
        uint isEq = (i < N0 && k == T) ? 1u : 0u;
        scanbuf[tid] = isEq;
        __syncthreads();
        for (int off = 1; off < 256; off <<= 1) {
            uint v = scanbuf[tid];
            uint add = (tid >= off) ? scanbuf[tid - off] : 0u;
            __syncthreads();
            scanbuf[tid] = v + add;
            __syncthreads();
        }
        uint incl = scanbuf[tid];
        uint total = scanbuf[255];
        if (i < N0) {
            uint excl = incl - isEq;
            uchar s = 0;
            if (k > T) s = 1;
            else if (isEq && (runningEq + excl) < needEq) s = 1;
            sl[i] = s;
        }
        runningEq += total;
        __syncthreads();
    }
}

// ---------- conv2 (graph 0 edges filtered by selection) ----------
__global__ void k_deg2(const int* src, const int* dst, const uchar* sel, uint* deg2) {
    int e = blockIdx.x * blockDim.x + threadIdx.x;
    if (e < NE) {
        int s = src[e], d = dst[e];
        if (sel[s] && sel[d]) atomicAdd(&deg2[d], 1u);
    }
}

__global__ void k_xw2(const float* h1, const float* score, const uchar* sel,
                      const float* W2, float* xw2) {
    int gt = blockIdx.x * blockDim.x + threadIdx.x;
    int i = gt >> 5, c = gt & 31;
    if (i >= N0) return;
    if (!sel[i]) return;
    float t = tanhf(score[i]);
    const float* row = h1 + (size_t)i * H1C;
    float acc = 0.f;
#pragma unroll
    for (int h = 0; h < H1C; h++) acc += row[h] * W2[h * H2C + c];
    xw2[i * H2C + c] = acc * t;
}

__global__ void k_msg2(const int* src, const int* dst, const uchar* sel,
                       const float* dinv2, const float* xw2, float* acc2) {
    int gt = blockIdx.x * blockDim.x + threadIdx.x;
    int e = gt >> 5, c = gt & 31;
    if (e >= NE) return;
    int s = src[e], d = dst[e];
    if (!(sel[s] && sel[d])) return;
    float norm = dinv2[s] * dinv2[d];
    atomicAdd(&acc2[d * H2C + c], xw2[s * H2C + c] * norm);
}

__global__ void k_fin2(const float* acc2, const float* xw2, const float* dinv2,
                       const uchar* sel, const float* b2, float* gmax) {
    __shared__ float m[32];
    int tid = threadIdx.x;
    if (tid < 32) m[tid] = 0.f;
    __syncthreads();
    int i = blockIdx.x * 8 + (tid >> 5);
    int c = tid & 31;
    float v = 0.f;
    if (i < N0 && sel[i]) {
        float di = dinv2[i];
        v = fmaxf(acc2[i * H2C + c] + xw2[i * H2C + c] * di * di + b2[c], 0.f);
    }
    atomicMax((int*)&m[c], __float_as_int(v));
    __syncthreads();
    if (tid < 32) atomicMax((int*)&gmax[tid], __float_as_int(m[tid]));
}

// ---------- graphs 1..63: h2 + max pool, recompute h1 from x ----------
#define BPG 4297  // ceil(N0/4)
__global__ void k_rest_pool(const float* x, const float* score, const uchar* sel,
                            const float* W1, const float* b1,
                            const float* W2, const float* b2, float* gmax) {
    __shared__ float xp[4][H1C];
    __shared__ float m[32];
    __shared__ float sW2[H1C * H2C];
    int tid = threadIdx.x;
    for (int i = tid; i < H1C * H2C; i += 256) sW2[i] = W2[i];
    if (tid < 32) m[tid] = 0.f;
    int g = blockIdx.x / BPG + 1;
    int li = (blockIdx.x % BPG) * 4 + (tid >> 6);
    int lane = tid & 63;
    int wv = tid >> 6;
    int n = g * N0 + li;
    bool valid = (li < N0) && sel[n];
    float xpv = 0.f;
    if (valid) {
        float acc = b1[lane];
#pragma unroll
        for (int f = 0; f < FIN; f++) acc += x[(size_t)n * FIN + f] * W1[f * H1C + lane];
        xpv = fmaxf(acc, 0.f) * tanhf(score[n]);
    }
    xp[wv][lane] = xpv;
    __syncthreads();
    float v = 0.f;
    if (valid && lane < 32) {
        float acc = b2[lane];
#pragma unroll
        for (int h = 0; h < H1C; h++) acc += xp[wv][h] * sW2[h * H2C + lane];
        v = fmaxf(acc, 0.f);
    }
    atomicMax((int*)&m[lane & 31], __float_as_int(v));
    __syncthreads();
    if (tid < 32) atomicMax((int*)&gmax[g * H2C + tid], __float_as_int(m[tid]));
}

// ---------- readout ----------
__global__ void k_final(const float* gmax, const float* Wf, const float* bf, float* out) {
    int g = threadIdx.x;
    if (g < BATCH) {
        float acc = bf[0];
        for (int c = 0; c < H2C; c++) acc += gmax[g * H2C + c] * Wf[c];
        out[g] = 1.f / (1.f + expf(-acc));
    }
}

extern "C" void kernel_launch(void* const* d_in, const int* in_sizes, int n_in,
                              void* d_out, int out_size, void* d_ws, size_t ws_size,
                              hipStream_t stream) {
    const float* data = (const float*)d_in[0];
    const void*  ei   = d_in[1];
    const float* W1   = (const float*)d_in[2];
    const float* b1   = (const float*)d_in[3];
    const float* Wp   = (const float*)d_in[4];
    const float* bp   = (const float*)d_in[5];
    const float* W2   = (const float*)d_in[6];
    const float* b2   = (const float*)d_in[7];
    const float* Wf   = (const float*)d_in[8];
    const float* bf   = (const float*)d_in[9];
    float* out = (float*)d_out;

    char* ws = (char*)d_ws;
    size_t off = 0;
    auto A = [&](size_t bytes) -> size_t {
        size_t o = off; off += (bytes + 511) & ~(size_t)511; return o;
    };
    // zero-initialized region (single memset)
    size_t o_acc1 = A((size_t)N0 * H1C * 4);
    size_t o_acc2 = A((size_t)N0 * H2C * 4);
    size_t o_sacc = A((size_t)N0 * 4);
    size_t o_deg0 = A((size_t)N0 * 4);
    size_t o_deg2 = A((size_t)N0 * 4);
    size_t o_gmax = A((size_t)BATCH * H2C * 4);
    size_t zbytes = off;
    // rest
    size_t o_src  = A((size_t)NE * 4);
    size_t o_dst  = A((size_t)NE * 4);
    size_t o_xw1  = A((size_t)N0 * H1C * 4);
    size_t o_di0  = A((size_t)N0 * 4);
    size_t o_di2  = A((size_t)N0 * 4);
    size_t o_h1w  = A((size_t)N0 * 4);
    size_t o_scr  = A((size_t)NT * 4);
    size_t o_sel  = A((size_t)NT);
    size_t o_xw2  = A((size_t)N0 * H2C * 4);
    size_t o_flag = A(4);

    float* acc1 = (float*)(ws + o_acc1);
    float* acc2 = (float*)(ws + o_acc2);
    float* sacc = (float*)(ws + o_sacc);
    uint*  deg0 = (uint*)(ws + o_deg0);
    uint*  deg2 = (uint*)(ws + o_deg2);
    float* gmax = (float*)(ws + o_gmax);
    int*   src  = (int*)(ws + o_src);
    int*   dst  = (int*)(ws + o_dst);
    float* xw1  = (float*)(ws + o_xw1);
    float* di0  = (float*)(ws + o_di0);
    float* di2  = (float*)(ws + o_di2);
    float* h1w  = (float*)(ws + o_h1w);
    float* scr  = (float*)(ws + o_scr);
    uchar* sel  = (uchar*)(ws + o_sel);
    float* xw2  = (float*)(ws + o_xw2);
    int*   flag = (int*)(ws + o_flag);

    hipMemsetAsync(ws, 0, zbytes, stream);

    k_detect<<<1, 256, 0, stream>>>((const uint*)ei, flag);
    k_convert<<<2048, 256, 0, stream>>>(ei, flag, src, dst);
    k_deg<<<(NE + 255) / 256, 256, 0, stream>>>(dst, deg0);
    k_xw1<<<(N0 * H1C + 255) / 256, 256, 0, stream>>>(data, W1, xw1);
    k_dinv<<<(N0 + 255) / 256, 256, 0, stream>>>(deg0, di0);
    k_msg1<<<(NE * 64 + 255) / 256, 256, 0, stream>>>(src, dst, di0, xw1, acc1);
    k_fin1<<<(N0 * H1C + 255) / 256, 256, 0, stream>>>(xw1, di0, b1, acc1);
    k_h1w<<<(N0 * 64 + 255) / 256, 256, 0, stream>>>(acc1, Wp, h1w);
    k_smsg<<<(NE + 255) / 256, 256, 0, stream>>>(src, dst, di0, h1w, sacc);
    k_score0<<<(N0 + 255) / 256, 256, 0, stream>>>(sacc, h1w, di0, bp, scr);
    {
        long long waves = (long long)(NT - N0);
        long long blocks = (waves * 64 + 255) / 256;
        k_score_rest<<<(int)blocks, 256, 0, stream>>>(data, W1, b1, Wp, bp, scr);
    }
    k_topk<<<BATCH, 256, 0, stream>>>(scr, sel);
    k_deg2<<<(NE + 255) / 256, 256, 0, stream>>>(src, dst, sel, deg2);
    k_dinv<<<(N0 + 255) / 256, 256, 0, stream>>>(deg2, di2);
    k_xw2<<<(N0 * 32 + 255) / 256, 256, 0, stream>>>(acc1, scr, sel, W2, xw2);
    k_msg2<<<(NE * 32 + 255) / 256, 256, 0, stream>>>(src, dst, sel, di2, xw2, acc2);
    k_fin2<<<(N0 + 7) / 8, 256, 0, stream>>>(acc2, xw2, di2, sel, b2, gmax);
    k_rest_pool<<<(BATCH - 1) * BPG, 256, 0, stream>>>(data, scr, sel, W1, b1, W2, b2, gmax);
    k_final<<<1, 64, 0, stream>>>(gmax, Wf, bf, out);
}

// Round 2
// 901.028 us; speedup vs baseline: 1.5085x; 1.5085x over previous
//
#include <hip/hip_runtime.h>
#include <math.h>

#define N0   17186
#define FIN  6
#define H1C  64
#define H2C  32
#define KSEL 12031
#define BATCH 64
#define NE   500000
#define NT   (BATCH * N0)

typedef unsigned int uint;
typedef unsigned char uchar;

__device__ __forceinline__ uint keyOf(float f) {
    uint u = __float_as_uint(f);
    return (u & 0x80000000u) ? ~u : (u | 0x80000000u);
}

// ---------- edge dtype detection / normalization ----------
__global__ void k_detect(const uint* ei, int* flag64) {
    __shared__ int any;
    if (threadIdx.x == 0) any = 0;
    __syncthreads();
    for (int i = threadIdx.x; i < 1024; i += blockDim.x)
        if (ei[2 * i + 1] != 0u) any = 1;
    __syncthreads();
    if (threadIdx.x == 0) *flag64 = any ? 0 : 1;
}

__global__ void k_convert(const void* ei, const int* flag64, int* src, int* dst) {
    int f = *flag64;
    int stride = gridDim.x * blockDim.x;
    for (int i = blockIdx.x * blockDim.x + threadIdx.x; i < 2 * NE; i += stride) {
        int v = f ? (int)((const long long*)ei)[i] : ((const int*)ei)[i];
        if (i < NE) src[i] = v; else dst[i - NE] = v;
    }
}

// ---------- CSR build ----------
__global__ void k_deg(const int* dst, uint* deg) {
    int e = blockIdx.x * blockDim.x + threadIdx.x;
    if (e < NE) atomicAdd(&deg[dst[e]], 1u);
}

__global__ void k_scan(const uint* deg, int* rowptr) {
    __shared__ uint tsum[256];
    int tid = threadIdx.x;
    const int CH = (N0 + 255) / 256;  // 68
    int beg = tid * CH, end = beg + CH;
    if (end > N0) end = N0;
    uint s = 0;
    for (int i = beg; i < end; i++) s += deg[i];
    tsum[tid] = s;
    __syncthreads();
    for (int off = 1; off < 256; off <<= 1) {
        uint v = tsum[tid];
        uint a = (tid >= off) ? tsum[tid - off] : 0u;
        __syncthreads();
        tsum[tid] = v + a;
        __syncthreads();
    }
    uint run = (tid > 0) ? tsum[tid - 1] : 0u;
    for (int i = beg; i < end; i++) { rowptr[i] = (int)run; run += deg[i]; }
    if (tid == 255) rowptr[N0] = (int)run;
}

__global__ void k_scatter(const int* src, const int* dst, const int* rowptr,
                          uint* cnt, int* csr) {
    int e = blockIdx.x * blockDim.x + threadIdx.x;
    if (e < NE) {
        int d = dst[e];
        uint p = atomicAdd(&cnt[d], 1u);
        csr[rowptr[d] + (int)p] = src[e];
    }
}

// ---------- conv1 (graph 0) ----------
__global__ void k_xw1(const float* x, const float* W1, float* xw1) {
    int t = blockIdx.x * blockDim.x + threadIdx.x;
    if (t >= N0 * H1C) return;
    int i = t >> 6, h = t & 63;
    float acc = 0.f;
#pragma unroll
    for (int f = 0; f < FIN; f++) acc += x[i * FIN + f] * W1[f * H1C + h];
    xw1[t] = acc;
}

__global__ void k_dinv(const uint* deg, float* dinv) {
    int i = blockIdx.x * blockDim.x + threadIdx.x;
    if (i < N0) dinv[i] = rsqrtf(1.0f + (float)deg[i]);
}

// gather conv1 messages + finish h1 (fused fin1)
__global__ void k_gath1(const int* rowptr, const int* csr, const float* dinv,
                        const float* xw1, const float* b1, float* h1) {
    int wid = (blockIdx.x * blockDim.x + threadIdx.x) >> 6;
    int lane = threadIdx.x & 63;
    if (wid >= N0) return;
    int d = wid;
    int beg = rowptr[d], end = rowptr[d + 1];
    float acc = 0.f;
    for (int e = beg; e < end; e++) {
        int s = csr[e];
        acc += xw1[(size_t)s * H1C + lane] * dinv[s];
    }
    float did = dinv[d];
    float v = acc * did + xw1[(size_t)d * H1C + lane] * did * did + b1[lane];
    h1[(size_t)d * H1C + lane] = fmaxf(v, 0.f);
}

// ---------- pooling score ----------
__global__ void k_h1w(const float* h1, const float* Wp, float* h1w) {
    int i = blockIdx.x * blockDim.x + threadIdx.x;
    if (i >= N0) return;
    const float* row = h1 + (size_t)i * H1C;
    float acc = 0.f;
#pragma unroll
    for (int h = 0; h < H1C; h++) acc += row[h] * Wp[h];
    h1w[i] = acc;
}

// graph-0 score: gather + self-loop (fused smsg+score0)
__global__ void k_gscore0(const int* rowptr, const int* csr, const float* dinv,
                          const float* h1w, const float* bp, float* score) {
    int d = blockIdx.x * blockDim.x + threadIdx.x;
    if (d >= N0) return;
    float acc = 0.f;
    int beg = rowptr[d], end = rowptr[d + 1];
    for (int e = beg; e < end; e++) {
        int s = csr[e];
        acc += h1w[s] * dinv[s];
    }
    float did = dinv[d];
    score[d] = acc * did + h1w[d] * did * did + bp[0];
}

// graphs 1..63: score = relu(x@W1+b1) . Wp + bp  (thread per node)
__global__ void k_score_rest(const float* x, const float* W1, const float* b1,
                             const float* Wp, const float* bp, float* score) {
    int idx = blockIdx.x * blockDim.x + threadIdx.x;
    int n = N0 + idx;
    if (n >= NT) return;
    float xr[FIN];
#pragma unroll
    for (int f = 0; f < FIN; f++) xr[f] = x[(size_t)n * FIN + f];
    float sc = bp[0];
#pragma unroll
    for (int h = 0; h < H1C; h++) {
        float a = b1[h];
#pragma unroll
        for (int f = 0; f < FIN; f++) a += xr[f] * W1[f * H1C + h];
        sc += fmaxf(a, 0.f) * Wp[h];
    }
    score[n] = sc;
}

// ---------- per-graph top-K selection (radix select on float keys) ----------
__global__ void k_topk(const float* score, uchar* sel) {
    int g = blockIdx.x;
    const float* sc = score + (size_t)g * N0;
    uchar* sl = sel + (size_t)g * N0;
    __shared__ uint hist[256];
    __shared__ uint shPrefix, shWant;
    __shared__ uint wtot[4];
    int tid = threadIdx.x;
    uint prefix = 0, want = KSEL;
    for (int pass = 0; pass < 4; pass++) {
        int shift = 24 - 8 * pass;
        hist[tid] = 0;
        __syncthreads();
        for (int i = tid; i < N0; i += 256) {
            uint k = keyOf(sc[i]);
            bool active = (pass == 0) || ((k >> (shift + 8)) == prefix);
            if (active) atomicAdd(&hist[(k >> shift) & 255], 1u);
        }
        __syncthreads();
        if (tid == 0) {
            uint cum = 0; int d = 255;
            for (; d > 0; d--) { cum += hist[d]; if (cum >= want) break; }
            if (cum < want) cum += hist[0];           // d==0 fallthrough
            shWant = want - (cum - hist[d]);
            shPrefix = (prefix << 8) | (uint)d;
        }
        __syncthreads();
        prefix = shPrefix; want = shWant;
        __syncthreads();
    }
    uint T = prefix, needEq = want;
    uint runningEq = 0;
    int wave = tid >> 6, lane = tid & 63;
    for (int base = 0; base < N0; base += 256) {
        int i = base + tid;
        uint k = (i < N0) ? keyOf(sc[i]) : 0u;
        bool isEq = (i < N0) && (k == T);
        unsigned long long mask = __ballot(isEq);
        uint wprefix = (uint)__popcll(mask & ((1ull << lane) - 1ull));
        uint wcount = (uint)__popcll(mask);
        if (lane == 0) wtot[wave] = wcount;
        __syncthreads();
        uint before = 0;
#pragma unroll
        for (int w = 0; w < 4; w++) if (w < wave) before += wtot[w];
        uint total = wtot[0] + wtot[1] + wtot[2] + wtot[3];
        if (i < N0) {
            uchar s = 0;
            if (k > T) s = 1;
            else if (isEq && (runningEq + before + wprefix) < needEq) s = 1;
            sl[i] = s;
        }
        runningEq += total;
        __syncthreads();
    }
}

// ---------- conv2 (graph 0, selection-filtered) ----------
// dinv2[d] = sel[d] ? rsqrt(1 + #selected in-edges) : 0   (0 acts as edge mask)
__global__ void k_gdinv2(const int* rowptr, const int* csr, const uchar* sel,
                         float* dinv2) {
    int d = blockIdx.x * blockDim.x + threadIdx.x;
    if (d >= N0) return;
    float r = 0.f;
    if (sel[d]) {
        int c = 0;
        int beg = rowptr[d], end = rowptr[d + 1];
        for (int e = beg; e < end; e++) c += sel[csr[e]];
        r = rsqrtf(1.f + (float)c);
    }
    dinv2[d] = r;
}

__global__ void k_xw2(const float* h1, const float* score, const uchar* sel,
                      const float* W2, float* xw2) {
    int gt = blockIdx.x * blockDim.x + threadIdx.x;
    int i = gt >> 5, c = gt & 31;
    if (i >= N0) return;
    if (!sel[i]) return;
    float t = tanhf(score[i]);
    const float* row = h1 + (size_t)i * H1C;
    float acc = 0.f;
#pragma unroll
    for (int h = 0; h < H1C; h++) acc += row[h] * W2[h * H2C + c];
    xw2[i * H2C + c] = acc * t;
}

__global__ void k_gath2(const int* rowptr, const int* csr, const uchar* sel,
                        const float* dinv2, const float* xw2, float* acc2) {
    int wid = (blockIdx.x * blockDim.x + threadIdx.x) >> 6;
    int lane = threadIdx.x & 63;
    if (wid >= N0) return;
    int d = wid;
    if (!sel[d]) return;
    int c = lane & 31;
    int beg = rowptr[d], end = rowptr[d + 1];
    float acc = 0.f;
    for (int e = beg + (lane >> 5); e < end; e += 2) {
        int s = csr[e];
        acc += xw2[(size_t)s * H2C + c] * dinv2[s];   // dinv2=0 masks unselected src
    }
    acc += __shfl_xor(acc, 32, 64);
    if (lane < 32) acc2[(size_t)d * H2C + c] = acc * dinv2[d];
}

__global__ void k_fin2(const float* acc2, const float* xw2, const float* dinv2,
                       const uchar* sel, const float* b2, float* gmax) {
    __shared__ float m[32];
    int tid = threadIdx.x;
    if (tid < 32) m[tid] = 0.f;
    __syncthreads();
    int i = blockIdx.x * 8 + (tid >> 5);
    int c = tid & 31;
    float v = 0.f;
    if (i < N0 && sel[i]) {
        float di = dinv2[i];
        v = fmaxf(acc2[(size_t)i * H2C + c] + xw2[(size_t)i * H2C + c] * di * di + b2[c], 0.f);
    }
    atomicMax((int*)&m[c], __float_as_int(v));
    __syncthreads();
    if (tid < 32) atomicMax((int*)&gmax[tid], __float_as_int(m[tid]));
}

// ---------- W2 transpose (for uniform scalar-load columns) ----------
__global__ void k_w2t(const float* W2, float* W2T) {
    for (int i = threadIdx.x; i < H1C * H2C; i += 256) {
        int h = i >> 5, c = i & 31;
        W2T[c * H1C + h] = W2[i];
    }
}

// ---------- graphs 1..63: h2 + max pool (thread per node, no LDS) ----------
#define WPG ((N0 + 63) / 64)   // 269 waves per graph
__global__ void k_rest_pool(const float* x, const float* score, const uchar* sel,
                            const float* W1, const float* b1,
                            const float* W2T, const float* b2, float* gmax) {
    int wid = (blockIdx.x * blockDim.x + threadIdx.x) >> 6;
    int lane = threadIdx.x & 63;
    int g = wid / WPG + 1;
    if (g >= BATCH) return;
    int li = (wid % WPG) * 64 + lane;
    bool inb = li < N0;
    int n = g * N0 + (inb ? li : (N0 - 1));
    bool valid = inb && sel[n];
    float xr[FIN];
#pragma unroll
    for (int f = 0; f < FIN; f++) xr[f] = 0.f;
    if (valid) {
        const float* xp = x + (size_t)n * FIN;
#pragma unroll
        for (int f = 0; f < FIN; f++) xr[f] = xp[f];
    }
    float h1r[H1C];
#pragma unroll
    for (int h = 0; h < H1C; h++) {
        float a = b1[h];
#pragma unroll
        for (int f = 0; f < FIN; f++) a += xr[f] * W1[f * H1C + h];
        h1r[h] = fmaxf(a, 0.f);
    }
    float t = valid ? tanhf(score[n]) : 0.f;
    float* gm = gmax + g * H2C;
    for (int c = 0; c < H2C; c++) {
        const float* wcol = W2T + c * H1C;
        float acc = 0.f;
#pragma unroll
        for (int h = 0; h < H1C; h++) acc += h1r[h] * wcol[h];
        float v = valid ? fmaxf(t * acc + b2[c], 0.f) : 0.f;
#pragma unroll
        for (int o = 32; o > 0; o >>= 1) v = fmaxf(v, __shfl_xor(v, o, 64));
        if (lane == 0) atomicMax((int*)&gm[c], __float_as_int(v));
    }
}

// ---------- readout ----------
__global__ void k_final(const float* gmax, const float* Wf, const float* bf, float* out) {
    int g = threadIdx.x;
    if (g < BATCH) {
        float acc = bf[0];
        for (int c = 0; c < H2C; c++) acc += gmax[g * H2C + c] * Wf[c];
        out[g] = 1.f / (1.f + expf(-acc));
    }
}

extern "C" void kernel_launch(void* const* d_in, const int* in_sizes, int n_in,
                              void* d_out, int out_size, void* d_ws, size_t ws_size,
                              hipStream_t stream) {
    const float* data = (const float*)d_in[0];
    const void*  ei   = d_in[1];
    const float* W1   = (const float*)d_in[2];
    const float* b1   = (const float*)d_in[3];
    const float* Wp   = (const float*)d_in[4];
    const float* bp   = (const float*)d_in[5];
    const float* W2   = (const float*)d_in[6];
    const float* b2   = (const float*)d_in[7];
    const float* Wf   = (const float*)d_in[8];
    const float* bf   = (const float*)d_in[9];
    float* out = (float*)d_out;

    char* ws = (char*)d_ws;
    size_t off = 0;
    auto A = [&](size_t bytes) -> size_t {
        size_t o = off; off += (bytes + 511) & ~(size_t)511; return o;
    };
    // zero-initialized region (single memset)
    size_t o_deg0 = A((size_t)N0 * 4);
    size_t o_cnt  = A((size_t)N0 * 4);
    size_t o_gmax = A((size_t)BATCH * H2C * 4);
    size_t zbytes = off;
    // rest
    size_t o_src  = A((size_t)NE * 4);
    size_t o_dst  = A((size_t)NE * 4);
    size_t o_rp   = A((size_t)(N0 + 1) * 4);
    size_t o_csr  = A((size_t)NE * 4);
    size_t o_xw1  = A((size_t)N0 * H1C * 4);
    size_t o_h1   = A((size_t)N0 * H1C * 4);
    size_t o_di0  = A((size_t)N0 * 4);
    size_t o_di2  = A((size_t)N0 * 4);
    size_t o_h1w  = A((size_t)N0 * 4);
    size_t o_scr  = A((size_t)NT * 4);
    size_t o_sel  = A((size_t)NT);
    size_t o_xw2  = A((size_t)N0 * H2C * 4);
    size_t o_acc2 = A((size_t)N0 * H2C * 4);
    size_t o_w2t  = A((size_t)H1C * H2C * 4);
    size_t o_flag = A(4);

    uint*  deg0 = (uint*)(ws + o_deg0);
    uint*  cnt  = (uint*)(ws + o_cnt);
    float* gmax = (float*)(ws + o_gmax);
    int*   src  = (int*)(ws + o_src);
    int*   dst  = (int*)(ws + o_dst);
    int*   rp   = (int*)(ws + o_rp);
    int*   csr  = (int*)(ws + o_csr);
    float* xw1  = (float*)(ws + o_xw1);
    float* h1   = (float*)(ws + o_h1);
    float* di0  = (float*)(ws + o_di0);
    float* di2  = (float*)(ws + o_di2);
    float* h1w  = (float*)(ws + o_h1w);
    float* scr  = (float*)(ws + o_scr);
    uchar* sel  = (uchar*)(ws + o_sel);
    float* xw2  = (float*)(ws + o_xw2);
    float* acc2 = (float*)(ws + o_acc2);
    float* w2t  = (float*)(ws + o_w2t);
    int*   flag = (int*)(ws + o_flag);

    hipMemsetAsync(ws, 0, zbytes, stream);

    k_detect<<<1, 256, 0, stream>>>((const uint*)ei, flag);
    k_convert<<<2048, 256, 0, stream>>>(ei, flag, src, dst);
    k_deg<<<(NE + 255) / 256, 256, 0, stream>>>(dst, deg0);
    k_scan<<<1, 256, 0, stream>>>(deg0, rp);
    k_scatter<<<(NE + 255) / 256, 256, 0, stream>>>(src, dst, rp, cnt, csr);
    k_w2t<<<1, 256, 0, stream>>>(W2, w2t);
    k_xw1<<<(N0 * H1C + 255) / 256, 256, 0, stream>>>(data, W1, xw1);
    k_dinv<<<(N0 + 255) / 256, 256, 0, stream>>>(deg0, di0);
    k_gath1<<<(N0 * 64 + 255) / 256, 256, 0, stream>>>(rp, csr, di0, xw1, b1, h1);
    k_h1w<<<(N0 + 255) / 256, 256, 0, stream>>>(h1, Wp, h1w);
    k_gscore0<<<(N0 + 255) / 256, 256, 0, stream>>>(rp, csr, di0, h1w, bp, scr);
    k_score_rest<<<(NT - N0 + 255) / 256, 256, 0, stream>>>(data, W1, b1, Wp, bp, scr);
    k_topk<<<BATCH, 256, 0, stream>>>(scr, sel);
    k_gdinv2<<<(N0 + 255) / 256, 256, 0, stream>>>(rp, csr, sel, di2);
    k_xw2<<<(N0 * H2C + 255) / 256, 256, 0, stream>>>(h1, scr, sel, W2, xw2);
    k_gath2<<<(N0 * 64 + 255) / 256, 256, 0, stream>>>(rp, csr, sel, di2, xw2, acc2);
    k_fin2<<<(N0 + 7) / 8, 256, 0, stream>>>(acc2, xw2, di2, sel, b2, gmax);
    {
        int waves = (BATCH - 1) * WPG;          // 63 * 269
        int blocks = (waves + 3) / 4;           // 4 waves / block
        k_rest_pool<<<blocks, 256, 0, stream>>>(data, scr, sel, W1, b1, w2t, b2, gmax);
    }
    k_final<<<1, 64, 0, stream>>>(gmax, Wf, bf, out);
}